// Round 1
// baseline (699.308 us; speedup 1.0000x reference)
//
#include <hip/hip_runtime.h>
#include <hip/hip_bf16.h>
#include <hip/hip_fp16.h>

#define NTOK 2048
#define DDIM 512
#define POOLN 65536
#define HIDN 256
#define CHIDN 128
#define KMAXN 256
#define CHUNK 512

typedef __attribute__((ext_vector_type(8))) short short8;
typedef __attribute__((ext_vector_type(4))) float f32x4;

__device__ __forceinline__ unsigned short f2bf(float f) {
  unsigned int u = __float_as_uint(f);
  unsigned int r = (u + 0x7FFFu + ((u >> 16) & 1u)) >> 16;
  return (unsigned short)r;
}
__device__ __forceinline__ float bf2f(unsigned short u) {
  return __uint_as_float(((unsigned int)u) << 16);
}
__device__ __forceinline__ void gl2lds16(const void* g, void* l) {
  __builtin_amdgcn_global_load_lds(
      (const __attribute__((address_space(1))) unsigned int*)g,
      (__attribute__((address_space(3))) unsigned int*)l, 16, 0, 0);
}

// ---------------- elementwise fp32 -> bf16 ----------------
__global__ void k_cvt_bf16(const float* __restrict__ in, unsigned short* __restrict__ out) {
  int i = (blockIdx.x * 256 + threadIdx.x) * 4;
  float4 v = *(const float4*)(in + i);
  ushort4 r;
  r.x = f2bf(v.x); r.y = f2bf(v.y); r.z = f2bf(v.z); r.w = f2bf(v.w);
  *(ushort4*)(out + i) = r;
}

// ---------------- transpose+convert: fp32 [K][N] -> bf16 [N][K] ----------------
__global__ void k_transpose_bf16(const float* __restrict__ src, unsigned short* __restrict__ dst,
                                 int K, int N) {
  __shared__ unsigned short s[64][72];
  int n0 = blockIdx.x * 64, k0 = blockIdx.y * 64;
  int t = threadIdx.x;
  int c = t & 63, kr = t >> 6;
  for (int i = 0; i < 16; i++) {
    int k = i * 4 + kr;
    s[c][k] = f2bf(src[(size_t)(k0 + k) * N + n0 + c]);
  }
  __syncthreads();
  for (int i = 0; i < 2; i++) {
    int idx = i * 256 + t;
    int n = idx >> 3, ch = idx & 7;
    uint4 v = *(const uint4*)&s[n][ch * 8];
    *(uint4*)(dst + (size_t)(n0 + n) * K + k0 + ch * 8) = v;
  }
}

// ---------------- MFMA GEMM: A[M,K]bf16 @ BT[N,K]bf16 -> C[M,N] 2-byte ----------------
// EPI==0: C = fp16(acc + bias);  EPI==1: C = bf16(relu(acc + bias))
template <int EPI>
__global__ __launch_bounds__(256) void k_gemm(const unsigned short* __restrict__ A,
                                              const unsigned short* __restrict__ BT,
                                              const float* __restrict__ bias,
                                              unsigned short* __restrict__ C,
                                              int M, int N, int K) {
  __shared__ unsigned short Alds[128 * 64];
  __shared__ unsigned short Blds[128 * 64];
  int nTiles = N >> 7;
  int bt = blockIdx.x;
  int m0 = (bt / nTiles) << 7;
  int n0 = (bt % nTiles) << 7;
  int t = threadIdx.x;
  int w = t >> 6, l = t & 63;
  int wRow = (w >> 1) << 6, wCol = (w & 1) << 6;

  f32x4 acc[4][4] = {};
  int cc = (l & 7) << 3;

  for (int kb = 0; kb < K; kb += 64) {
#pragma unroll
    for (int i = 0; i < 4; i++) {
      int rbase = (w << 5) + (i << 3);
      int r = rbase + (l >> 3);
      gl2lds16(A + (size_t)(m0 + r) * K + kb + cc, &Alds[rbase << 6]);
      gl2lds16(BT + (size_t)(n0 + r) * K + kb + cc, &Blds[rbase << 6]);
    }
    __syncthreads();
#pragma unroll
    for (int ks = 0; ks < 64; ks += 32) {
      short8 af[4], bfr[4];
#pragma unroll
      for (int mi = 0; mi < 4; mi++)
        af[mi] = *(const short8*)&Alds[(wRow + (mi << 4) + (l & 15)) * 64 + ks + ((l >> 4) << 3)];
#pragma unroll
      for (int ni = 0; ni < 4; ni++)
        bfr[ni] = *(const short8*)&Blds[(wCol + (ni << 4) + (l & 15)) * 64 + ks + ((l >> 4) << 3)];
#pragma unroll
      for (int mi = 0; mi < 4; mi++)
#pragma unroll
        for (int ni = 0; ni < 4; ni++)
          acc[mi][ni] = __builtin_amdgcn_mfma_f32_16x16x32_bf16(af[mi], bfr[ni], acc[mi][ni], 0, 0, 0);
    }
    __syncthreads();
  }

#pragma unroll
  for (int ni = 0; ni < 4; ni++) {
    int col = n0 + wCol + (ni << 4) + (l & 15);
    float bv = bias[col];
#pragma unroll
    for (int mi = 0; mi < 4; mi++) {
      int row = m0 + wRow + (mi << 4) + ((l >> 4) << 2);
#pragma unroll
      for (int r = 0; r < 4; r++) {
        float v = acc[mi][ni][r] + bv;
        if (EPI == 1) {
          v = v > 0.f ? v : 0.f;
          C[(size_t)(row + r) * N + col] = f2bf(v);
        } else {
          _Float16 h = (_Float16)v;
          C[(size_t)(row + r) * N + col] = *(unsigned short*)&h;
        }
      }
    }
  }
}

// ---------------- router GEMV: logit = h1[row,:] . Wc2 -> budget ----------------
__global__ void k_router(const unsigned short* __restrict__ h1, const float* __restrict__ Wc2,
                         const float* __restrict__ bc2, int* __restrict__ budgets) {
  int t = threadIdx.x, w = t >> 6, l = t & 63;
  int row = blockIdx.x * 4 + w;
  float v = bf2f(h1[row * 128 + l]) * Wc2[l] + bf2f(h1[row * 128 + 64 + l]) * Wc2[64 + l];
  for (int o = 1; o < 64; o <<= 1) v += __shfl_xor(v, o);
  if (l == 0) {
    float c = 1.f / (1.f + expf(-(v + bc2[0])));
    float raw = 100.f + 156.f * c * c;
    raw = fminf(fmaxf(raw, 100.f), 256.f);
    budgets[row] = (int)rintf(raw);
  }
}

// ---------------- per-row exact top-256 + sort + masked softmax ----------------
__device__ void find_bin(unsigned int* hist, int bins, unsigned int need, int t,
                         unsigned int* S, unsigned int* res) {
  int per = bins >> 8;
  unsigned int s = 0;
  for (int i = 0; i < per; i++) s += hist[t * per + i];
  S[t] = s;
  __syncthreads();
  for (int off = 1; off < 256; off <<= 1) {
    unsigned int v = (t + off < 256) ? S[t + off] : 0u;
    __syncthreads();
    S[t] += v;
    __syncthreads();
  }
  if (t == 0) { res[0] = 0u; res[1] = 0u; }
  __syncthreads();
  bool hit = (S[t] >= need) && (t == 255 || S[t + 1] < need);
  if (hit) { res[0] = (unsigned int)t; res[1] = (t == 255) ? 0u : S[t + 1]; }
  __syncthreads();
  if (t == 0) {
    int g = (int)res[0];
    unsigned int cum = res[1];
    int binSel = g * per;
    for (int b = g * per + per - 1; b >= g * per; b--) {
      unsigned int h = hist[b];
      if (cum + h >= need) { binSel = b; break; }
      cum += h;
    }
    res[0] = (unsigned int)binSel;
    res[1] = cum;
  }
  __syncthreads();
}

__global__ __launch_bounds__(256) void k_topk(const unsigned short* __restrict__ scores,
                                              const int* __restrict__ budgets, int row0,
                                              int* __restrict__ topk_idx,
                                              float* __restrict__ topk_w) {
  __shared__ unsigned int hist[4096];
  __shared__ unsigned int cand[2048];
  __shared__ unsigned int sel[256];
  __shared__ unsigned int S[256];
  __shared__ unsigned int cnts[8];
  __shared__ float fred[8];

  int lrow = blockIdx.x;
  int grow = row0 + lrow;
  int t = threadIdx.x;
  const uint4* s4 = (const uint4*)(scores + (size_t)lrow * POOLN);

  for (int i = t; i < 4096; i += 256) hist[i] = 0;
  sel[t] = 0x03FF0000u;  // pad: score=-inf, idx=65535
  if (t < 8) cnts[t] = 0;
  __syncthreads();

  // pass 1: 4096-bin histogram of ordered fp16 keys
  for (int i = 0; i < 32; i++) {
    uint4 v = s4[i * 256 + t];
    unsigned int ww[4] = {v.x, v.y, v.z, v.w};
#pragma unroll
    for (int q = 0; q < 4; q++) {
      unsigned int b0 = ww[q] & 0xFFFFu, b1 = ww[q] >> 16;
      unsigned int k0 = b0 ^ ((b0 & 0x8000u) ? 0xFFFFu : 0x8000u);
      unsigned int k1 = b1 ^ ((b1 & 0x8000u) ? 0xFFFFu : 0x8000u);
      atomicAdd(&hist[k0 >> 4], 1u);
      atomicAdd(&hist[k1 >> 4], 1u);
    }
  }
  __syncthreads();
  find_bin(hist, 4096, 256u, t, S, &cnts[4]);
  unsigned int B = cnts[4];
  unsigned int cntAbove = cnts[5];
  unsigned int need = 256u - cntAbove;

  // pass 2: direct-select bins > B, collect candidates in bin B
  for (int i = 0; i < 32; i++) {
    uint4 v = s4[i * 256 + t];
    unsigned int ww[4] = {v.x, v.y, v.z, v.w};
    unsigned int baseIdx = (unsigned int)(i * 256 + t) * 8u;
#pragma unroll
    for (int q = 0; q < 4; q++) {
#pragma unroll
      for (int hh = 0; hh < 2; hh++) {
        unsigned int b0 = hh ? (ww[q] >> 16) : (ww[q] & 0xFFFFu);
        unsigned int k0 = b0 ^ ((b0 & 0x8000u) ? 0xFFFFu : 0x8000u);
        unsigned int bin = k0 >> 4;
        if (bin >= B) {
          unsigned int p = (k0 << 16) | (0xFFFFu ^ (baseIdx + q * 2u + hh));
          if (bin > B) {
            unsigned int pos = atomicAdd(&cnts[0], 1u);
            sel[pos] = p;
          } else {
            unsigned int pos = atomicAdd(&cnts[1], 1u);
            if (pos < 2048u) cand[pos] = p;
          }
        }
      }
    }
  }
  __syncthreads();
  int nc = (int)cnts[1]; if (nc > 2048) nc = 2048;

  // refine level A: bits [19:10]
  for (int i = t; i < 1024; i += 256) hist[i] = 0;
  __syncthreads();
  for (int i = t; i < nc; i += 256) atomicAdd(&hist[(cand[i] >> 10) & 0x3FFu], 1u);
  __syncthreads();
  find_bin(hist, 1024, need, t, S, &cnts[4]);
  unsigned int BA = cnts[4];
  unsigned int aboveA = cnts[5];
  unsigned int needB = need - aboveA;

  // refine level B: bits [9:0]
  for (int i = t; i < 1024; i += 256) hist[i] = 0;
  __syncthreads();
  for (int i = t; i < nc; i += 256) {
    unsigned int p = cand[i];
    if (((p >> 10) & 0x3FFu) == BA) atomicAdd(&hist[p & 0x3FFu], 1u);
  }
  __syncthreads();
  find_bin(hist, 1024, needB, t, S, &cnts[4]);
  unsigned int BB = cnts[4];
  unsigned int T = (B << 20) | (BA << 10) | BB;
  __syncthreads();
  for (int i = t; i < nc; i += 256) {
    unsigned int p = cand[i];
    if (p >= T) {
      unsigned int pos = atomicAdd(&cnts[0], 1u);
      if (pos < 256u) sel[pos] = p;
    }
  }
  __syncthreads();

  // bitonic sort sel[256] descending
  for (int k = 2; k <= 256; k <<= 1) {
    for (int j = k >> 1; j > 0; j >>= 1) {
      int ixj = t ^ j;
      if (ixj > t) {
        unsigned int a = sel[t], b = sel[ixj];
        bool up = ((t & k) == 0);
        bool sw = up ? (a < b) : (a > b);
        if (sw) { sel[t] = b; sel[ixj] = a; }
      }
      __syncthreads();
    }
  }

  // masked softmax
  unsigned int p = sel[t];
  unsigned int okey = p >> 16;
  int idx = (int)((p & 0xFFFFu) ^ 0xFFFFu);
  unsigned short hb = (unsigned short)((okey & 0x8000u) ? (okey ^ 0x8000u) : (okey ^ 0xFFFFu));
  union { unsigned short u; _Float16 f; } cvt;
  cvt.u = hb;
  float sc = (float)cvt.f;
  if (t == 0) fred[0] = sc;
  __syncthreads();
  float m = fred[0];
  float e = expf(sc - m);
  float r = e;
  for (int o = 1; o < 64; o <<= 1) r += __shfl_xor(r, o);
  if ((t & 63) == 0) fred[1 + (t >> 6)] = r;
  __syncthreads();
  float Z = fred[1] + fred[2] + fred[3] + fred[4];
  int budget = budgets[grow];
  float wgt = (t < budget) ? (e / Z) : 0.f;
  topk_idx[(size_t)grow * 256 + t] = idx;
  topk_w[(size_t)grow * 256 + t] = wgt;
}

// ---------------- executor: out = x + sum_k w_k * tanh(x.p_k) * p_k ----------------
__global__ __launch_bounds__(256) void k_exec(const float* __restrict__ x,
                                              const float* __restrict__ pool,
                                              const int* __restrict__ topk_idx,
                                              const float* __restrict__ topk_w,
                                              const int* __restrict__ budgets,
                                              float* __restrict__ out) {
  __shared__ float partial[4 * 512];
  __shared__ int kidx[256];
  __shared__ float kwt[256];
  int row = blockIdx.x;
  int t = threadIdx.x, w = t >> 6, l = t & 63;
  int budget = budgets[row];
  kidx[t] = topk_idx[(size_t)row * 256 + t];
  kwt[t] = topk_w[(size_t)row * 256 + t];
  __syncthreads();
  const float* xr = x + (size_t)row * 512;
  float4 x0 = *(const float4*)(xr + l * 8);
  float4 x1 = *(const float4*)(xr + l * 8 + 4);
  float4 a0 = {0, 0, 0, 0}, a1 = {0, 0, 0, 0};
  for (int k = w; k < budget; k += 4) {
    const float* pr = pool + (size_t)kidx[k] * 512;
    float4 p0 = *(const float4*)(pr + l * 8);
    float4 p1 = *(const float4*)(pr + l * 8 + 4);
    float d = p0.x * x0.x + p0.y * x0.y + p0.z * x0.z + p0.w * x0.w +
              p1.x * x1.x + p1.y * x1.y + p1.z * x1.z + p1.w * x1.w;
    for (int o = 1; o < 64; o <<= 1) d += __shfl_xor(d, o);
    float a = kwt[k] * tanhf(d);
    a0.x += a * p0.x; a0.y += a * p0.y; a0.z += a * p0.z; a0.w += a * p0.w;
    a1.x += a * p1.x; a1.y += a * p1.y; a1.z += a * p1.z; a1.w += a * p1.w;
  }
  *(float4*)&partial[w * 512 + l * 8] = a0;
  *(float4*)&partial[w * 512 + l * 8 + 4] = a1;
  __syncthreads();
  for (int i = 0; i < 2; i++) {
    int d = i * 256 + t;
    out[(size_t)row * 512 + d] =
        xr[d] + partial[d] + partial[512 + d] + partial[1024 + d] + partial[1536 + d];
  }
}

extern "C" void kernel_launch(void* const* d_in, const int* in_sizes, int n_in,
                              void* d_out, int out_size, void* d_ws, size_t ws_size,
                              hipStream_t stream) {
  const float* x    = (const float*)d_in[0];
  const float* pool = (const float*)d_in[1];
  const float* Wc1  = (const float*)d_in[2];
  const float* bc1  = (const float*)d_in[3];
  const float* Wc2  = (const float*)d_in[4];
  const float* bc2  = (const float*)d_in[5];
  const float* Ws1  = (const float*)d_in[6];
  const float* bs1  = (const float*)d_in[7];
  const float* Ws2  = (const float*)d_in[8];
  const float* bs2  = (const float*)d_in[9];
  float* out = (float*)d_out;

  char* ws = (char*)d_ws;
  size_t off = 0;
  auto alloc = [&](size_t bytes) {
    void* p = ws + off;
    off += (bytes + 255) & ~(size_t)255;
    return p;
  };
  unsigned short* x_bf   = (unsigned short*)alloc((size_t)NTOK * DDIM * 2);
  unsigned short* wc1t   = (unsigned short*)alloc((size_t)CHIDN * DDIM * 2);
  unsigned short* ws1t   = (unsigned short*)alloc((size_t)HIDN * DDIM * 2);
  unsigned short* ws2t   = (unsigned short*)alloc((size_t)POOLN * HIDN * 2);
  unsigned short* h1_bf  = (unsigned short*)alloc((size_t)NTOK * CHIDN * 2);
  unsigned short* h_bf   = (unsigned short*)alloc((size_t)NTOK * HIDN * 2);
  unsigned short* scores = (unsigned short*)alloc((size_t)CHUNK * POOLN * 2);
  int*   budgets  = (int*)alloc((size_t)NTOK * 4);
  int*   topk_idx = (int*)alloc((size_t)NTOK * 256 * 4);
  float* topk_w   = (float*)alloc((size_t)NTOK * 256 * 4);

  k_cvt_bf16<<<1024, 256, 0, stream>>>(x, x_bf);
  k_transpose_bf16<<<dim3(CHIDN / 64, DDIM / 64), 256, 0, stream>>>(Wc1, wc1t, DDIM, CHIDN);
  k_transpose_bf16<<<dim3(HIDN / 64, DDIM / 64), 256, 0, stream>>>(Ws1, ws1t, DDIM, HIDN);
  k_transpose_bf16<<<dim3(POOLN / 64, HIDN / 64), 256, 0, stream>>>(Ws2, ws2t, HIDN, POOLN);

  // h1 = relu(x @ Wc1 + bc1)  [2048,128]
  k_gemm<1><<<(NTOK / 128) * (CHIDN / 128), 256, 0, stream>>>(x_bf, wc1t, bc1, h1_bf,
                                                              NTOK, CHIDN, DDIM);
  k_router<<<NTOK / 4, 256, 0, stream>>>(h1_bf, Wc2, bc2, budgets);

  // h = relu(x @ Ws1 + bs1)  [2048,256]
  k_gemm<1><<<(NTOK / 128) * (HIDN / 128), 256, 0, stream>>>(x_bf, ws1t, bs1, h_bf,
                                                             NTOK, HIDN, DDIM);

  for (int c = 0; c < NTOK / CHUNK; c++) {
    k_gemm<0><<<(CHUNK / 128) * (POOLN / 128), 256, 0, stream>>>(
        h_bf + (size_t)c * CHUNK * HIDN, ws2t, bs2, scores, CHUNK, POOLN, HIDN);
    k_topk<<<CHUNK, 256, 0, stream>>>(scores, budgets, c * CHUNK, topk_idx, topk_w);
  }

  k_exec<<<NTOK, 256, 0, stream>>>(x, pool, topk_idx, topk_w, budgets, out);
}